// Round 7
// baseline (77.117 us; speedup 1.0000x reference)
//
#include <hip/hip_runtime.h>
#include <hip/hip_fp16.h>

// O = U X U^H, U = kron of 11 single-qubit SU(2) gates (2048^2 complex64).
// Reordered as O = U * (X * U^H):
//   K1 rowpassK1: Y = X U^H (butterflies over col index j, conj gates).
//      Round-5 verified split-plane b32 LDS + swz. 2 row-groups/block with
//      register prefetch of group 2 while group 1 computes.
//   K2 collowK2: column bits 0-6 (qubits 10..4), 128x32 tiles, 2 phases,
//      split-plane LDS [r*32+c] (bank-free). 2 tiles/block + prefetch.
//   K3 colhighK3: column bits 7-10 (qubits 3..0), registers only,
//      2 tiles/block + prefetch, writes Re(O) fp32.
// Round-6 post-mortem: b64 LDS regressed (even-bank aliasing) -> reverted.
// This round: intra-block tile pipelining to break the lockstep
// load|compute|store phase serialization identified in round 5/6.

#define DIM 2048
#define NQ 11

__device__ __forceinline__ int swz(int j) { return j ^ ((j >> 5) & 31); }

__device__ __forceinline__ float2 cmul(float2 a, float2 b) {
    return make_float2(a.x * b.x - a.y * b.y, a.x * b.y + a.y * b.x);
}

// Composite gate g = Rz @ Ry @ Rx for qubit q; conj!=0 -> conjugate entries.
__device__ __forceinline__ void make_gate(const float* __restrict__ w, int q,
                                          int conj, float2* out4) {
    const float WM = 0.632455532033675866f;  // sqrt(2/5)
    float hx = 0.5f * WM * w[q * 3 + 0];
    float hy = 0.5f * WM * w[q * 3 + 1];
    float hz = 0.5f * WM * w[q * 3 + 2];
    float cx, sx, cy, sy, cz, sz;
    sincosf(hx, &sx, &cx);
    sincosf(hy, &sy, &cy);
    sincosf(hz, &sz, &cz);
    float2 m00 = make_float2(cy * cx,  sy * sx);
    float2 m01 = make_float2(-sy * cx, -cy * sx);
    float2 m10 = make_float2(sy * cx,  -cy * sx);
    float2 m11 = make_float2(cy * cx,  -sy * sx);
    float2 ez  = make_float2(cz, -sz);
    float2 ezc = make_float2(cz,  sz);
    float2 g00 = cmul(ez, m00);
    float2 g01 = cmul(ez, m01);
    float2 g10 = cmul(ezc, m10);
    float2 g11 = cmul(ezc, m11);
    float sgn = conj ? -1.f : 1.f;
    out4[0] = make_float2(g00.x, sgn * g00.y);
    out4[1] = make_float2(g01.x, sgn * g01.y);
    out4[2] = make_float2(g10.x, sgn * g10.y);
    out4[3] = make_float2(g11.x, sgn * g11.y);
}

__device__ __forceinline__ void bfly(float2& A, float2& B, const float2* g) {
    float2 a = A, b = B;
    A = make_float2(g[0].x * a.x - g[0].y * a.y + g[1].x * b.x - g[1].y * b.y,
                    g[0].x * a.y + g[0].y * a.x + g[1].x * b.y + g[1].y * b.x);
    B = make_float2(g[2].x * a.x - g[2].y * a.y + g[3].x * b.x - g[3].y * b.y,
                    g[2].x * a.y + g[2].y * a.x + g[3].x * b.y + g[3].y * b.x);
}

template <int ST>
__device__ __forceinline__ void stage16(float2* v, const float2* g) {
#pragma unroll
    for (int m = 0; m < 16; ++m)
        if (!(m & ST)) bfly(v[m], v[m + ST], g);
}

__device__ __forceinline__ void load_gate(const float2 (*gsh)[4], int q,
                                          float2* g) {
    g[0] = gsh[q][0]; g[1] = gsh[q][1]; g[2] = gsh[q][2]; g[3] = gsh[q][3];
}

__device__ __forceinline__ unsigned pack_h2(float2 v) {
    __half2 h = __float22half2_rn(v);
    return *reinterpret_cast<unsigned*>(&h);
}
__device__ __forceinline__ float2 unpack_h2(unsigned u) {
    __half2 h = *reinterpret_cast<__half2*>(&u);
    return __half22float2(h);
}

// ---------------- K1: Y = X U^H (row transform) ----------------------------
// 256 thr, 2 rows per group, 2 groups per block (prefetched). Grid 512.
__global__ __launch_bounds__(256, 4) void rowpassK1(
    const float* __restrict__ X, unsigned* __restrict__ Y,
    const float* __restrict__ wt) {
    __shared__ float pRe[2 * DIM];
    __shared__ float pIm[2 * DIM];
    __shared__ float2 gsh[NQ][4];
    int t = threadIdx.x;
    if (t < NQ) make_gate(wt, t, 1, &gsh[t][0]);  // conjugated gates
    __syncthreads();

    int u = t & 127, rv = t >> 7;       // u = j bits 0-6, rv = row-in-group
    int base = rv * DIM;
    int row0 = blockIdx.x * 4 + rv;

    float xr[16], xn[16];
#pragma unroll
    for (int m = 0; m < 16; ++m)
        xr[m] = X[(size_t)row0 * DIM + u + (m << 7)];

    for (int grp = 0; grp < 2; ++grp) {
        int row = row0 + grp * 2;
        if (grp == 0) {
            // prefetch next group's inputs; consumed next iteration
#pragma unroll
            for (int m = 0; m < 16; ++m)
                xn[m] = X[(size_t)(row0 + 2) * DIM + u + (m << 7)];
        }

        // Phase A: j = u + 128m (bits 7-10 -> qubits 3,2,1,0). X real.
        float2 v[16], g[4];
        load_gate(gsh, 3, g);           // j bit 7, real-input stage
#pragma unroll
        for (int m = 0; m < 16; m += 2) {
            float a = xr[m], b = xr[m + 1];
            v[m]     = make_float2(g[0].x * a + g[1].x * b,
                                   g[0].y * a + g[1].y * b);
            v[m + 1] = make_float2(g[2].x * a + g[3].x * b,
                                   g[2].y * a + g[3].y * b);
        }
        load_gate(gsh, 2, g); stage16<2>(v, g);   // bit 8
        load_gate(gsh, 1, g); stage16<4>(v, g);   // bit 9
        load_gate(gsh, 0, g); stage16<8>(v, g);   // bit 10

#pragma unroll
        for (int m = 0; m < 16; ++m) {
            int a = base + swz(u + (m << 7));
            pRe[a] = v[m].x; pIm[a] = v[m].y;
        }
        __syncthreads();

        // Phase M: j = (u&7) + 8m + 128*(u>>3) (bits 3-6 -> qubits 7,6,5,4).
        int uLo = u & 7, uHi = u >> 3;
#pragma unroll
        for (int m = 0; m < 16; ++m) {
            int a = base + swz(uLo + (m << 3) + (uHi << 7));
            v[m] = make_float2(pRe[a], pIm[a]);
        }
        load_gate(gsh, 7, g); stage16<1>(v, g);
        load_gate(gsh, 6, g); stage16<2>(v, g);
        load_gate(gsh, 5, g); stage16<4>(v, g);
        load_gate(gsh, 4, g); stage16<8>(v, g);
#pragma unroll
        for (int m = 0; m < 16; ++m) {
            int a = base + swz(uLo + (m << 3) + (uHi << 7));
            pRe[a] = v[m].x; pIm[a] = v[m].y;
        }
        __syncthreads();

        // Phase F: j = m + 16u (bits 0-2 -> qubits 10,9,8).
#pragma unroll
        for (int m = 0; m < 16; ++m) {
            int a = base + swz(m + (u << 4));
            v[m] = make_float2(pRe[a], pIm[a]);
        }
        __syncthreads();   // LDS reads done; next group may overwrite
        load_gate(gsh, 10, g); stage16<1>(v, g);
        load_gate(gsh, 9, g);  stage16<2>(v, g);
        load_gate(gsh, 8, g);  stage16<4>(v, g);

        // Store fp16: thread holds 16 consecutive j = 16u..16u+15.
        unsigned* yp = Y + (size_t)row * DIM + (u << 4);
#pragma unroll
        for (int e = 0; e < 4; ++e) {
            uint4 pk;
            pk.x = pack_h2(v[4 * e + 0]);
            pk.y = pack_h2(v[4 * e + 1]);
            pk.z = pack_h2(v[4 * e + 2]);
            pk.w = pack_h2(v[4 * e + 3]);
            *reinterpret_cast<uint4*>(yp + 4 * e) = pk;
        }
#pragma unroll
        for (int m = 0; m < 16; ++m) xr[m] = xn[m];
    }
}

// -------- K2: column transform over row bits 0-6 (qubits 10..4) ------------
// Tile: 128 rows x 32 cols, 2 phases. 2 tiles/block (prefetched). Grid 512.
__global__ __launch_bounds__(256, 4) void collowK2(
    const unsigned* __restrict__ Y, unsigned* __restrict__ Z,
    const float* __restrict__ wt) {
    __shared__ float pRe[128 * 32];
    __shared__ float pIm[128 * 32];
    __shared__ float2 gsh[NQ][4];
    int t = threadIdx.x;
    if (t < NQ) make_gate(wt, t, 0, &gsh[t][0]);
    __syncthreads();

    int c = t & 31, rr = t >> 5;         // rr = d bits 0-2 (phase A)
    int r0a = (blockIdx.x >> 6) * 128;   // row groups 0..7; tile1 adds 1024
    int c0 = (blockIdx.x & 63) * 32;

    unsigned pr[16], pn[16];
#pragma unroll
    for (int m = 0; m < 16; ++m)
        pr[m] = Y[(size_t)(r0a + rr + (m << 3)) * DIM + c0 + c];

    for (int tile = 0; tile < 2; ++tile) {
        int r0 = r0a + tile * 1024;
        if (tile == 0) {
#pragma unroll
            for (int m = 0; m < 16; ++m)
                pn[m] = Y[(size_t)(r0a + 1024 + rr + (m << 3)) * DIM + c0 + c];
        }

        // Phase A: d = rr + 8m (bits 3-6 -> qubits 7,6,5,4).
        float2 v[16], g[4];
#pragma unroll
        for (int m = 0; m < 16; ++m) v[m] = unpack_h2(pr[m]);

        load_gate(gsh, 7, g); stage16<1>(v, g);
        load_gate(gsh, 6, g); stage16<2>(v, g);
        load_gate(gsh, 5, g); stage16<4>(v, g);
        load_gate(gsh, 4, g); stage16<8>(v, g);
#pragma unroll
        for (int m = 0; m < 16; ++m) {
            int a = (rr + (m << 3)) * 32 + c;
            pRe[a] = v[m].x; pIm[a] = v[m].y;
        }
        __syncthreads();

        // Phase F: d = m + 16rr (bits 0-2 -> qubits 10,9,8).
#pragma unroll
        for (int m = 0; m < 16; ++m) {
            int a = (m + (rr << 4)) * 32 + c;
            v[m] = make_float2(pRe[a], pIm[a]);
        }
        __syncthreads();   // LDS reads done; next tile may overwrite
        load_gate(gsh, 10, g); stage16<1>(v, g);
        load_gate(gsh, 9, g);  stage16<2>(v, g);
        load_gate(gsh, 8, g);  stage16<4>(v, g);

#pragma unroll
        for (int m = 0; m < 16; ++m)
            Z[(size_t)(r0 + m + (rr << 4)) * DIM + c0 + c] = pack_h2(v[m]);
#pragma unroll
        for (int m = 0; m < 16; ++m) pr[m] = pn[m];
    }
}

// -------- K3: column transform over row bits 7-10 (qubits 3..0) ------------
// No LDS: thread owns rows d + 128m for one column j. 2 tiles/block.
__global__ __launch_bounds__(256, 4) void colhighK3(
    const unsigned* __restrict__ Z, float* __restrict__ Out,
    const float* __restrict__ wt, int writeComplex) {
    __shared__ float2 gsh[NQ][4];
    int t = threadIdx.x;
    if (t < NQ) make_gate(wt, t, 0, &gsh[t][0]);
    __syncthreads();

    int bx = blockIdx.x;                 // 0..511; tiles bx and bx+512
    unsigned pr[16], pn[16];
    int j0 = (bx & 31) * 64 + (t & 63);
    int d0 = (bx >> 5) * 4 + (t >> 6);
#pragma unroll
    for (int m = 0; m < 16; ++m)
        pr[m] = Z[(size_t)(d0 + (m << 7)) * DIM + j0];

    for (int tile = 0; tile < 2; ++tile) {
        int be = bx + tile * 512;
        int j = (be & 31) * 64 + (t & 63);
        int d = (be >> 5) * 4 + (t >> 6);
        if (tile == 0) {
            int be2 = bx + 512;
            int j2 = (be2 & 31) * 64 + (t & 63);
            int d2 = (be2 >> 5) * 4 + (t >> 6);
#pragma unroll
            for (int m = 0; m < 16; ++m)
                pn[m] = Z[(size_t)(d2 + (m << 7)) * DIM + j2];
        }

        float2 v[16], g[4];
#pragma unroll
        for (int m = 0; m < 16; ++m) v[m] = unpack_h2(pr[m]);

        load_gate(gsh, 3, g); stage16<1>(v, g);   // row bit 7
        load_gate(gsh, 2, g); stage16<2>(v, g);   // bit 8
        load_gate(gsh, 1, g); stage16<4>(v, g);   // bit 9
        load_gate(gsh, 0, g); stage16<8>(v, g);   // bit 10

        if (!writeComplex) {
#pragma unroll
            for (int m = 0; m < 16; ++m)
                Out[(size_t)(d + (m << 7)) * DIM + j] = v[m].x;
        } else {
            float2* o2 = (float2*)Out;
#pragma unroll
            for (int m = 0; m < 16; ++m)
                o2[(size_t)(d + (m << 7)) * DIM + j] = v[m];
        }
#pragma unroll
        for (int m = 0; m < 16; ++m) pr[m] = pn[m];
    }
}

extern "C" void kernel_launch(void* const* d_in, const int* in_sizes, int n_in,
                              void* d_out, int out_size, void* d_ws,
                              size_t ws_size, hipStream_t stream) {
    const float* X = (const float*)d_in[0];
    const float* wt = (const float*)d_in[1];
    float* out = (float*)d_out;
    unsigned* Y = (unsigned*)d_ws;                                   // 16 MB
    unsigned* Z = (unsigned*)((char*)d_ws + (size_t)DIM * DIM * 4);  // 16 MB

    rowpassK1<<<512, 256, 0, stream>>>(X, Y, wt);
    collowK2<<<512, 256, 0, stream>>>(Y, Z, wt);
    int wc = (out_size >= 2 * DIM * DIM) ? 1 : 0;
    colhighK3<<<512, 256, 0, stream>>>(Z, out, wt, wc);
}

// Round 8
// 43.491 us; speedup vs baseline: 1.7732x; 1.7732x over previous
//
#include <hip/hip_runtime.h>
#include <hip/hip_fp16.h>

// O = U X U^H, U = kron of 11 single-qubit SU(2) gates (2048^2 complex64).
// Reordered as O = U * (X * U^H):
//   K1 rowpassK1: Y = X U^H (butterflies over col index j, conj gates).
//      256 thr, 2 rows/block, grid 1024. 3 register phases (j bits 7-10 |
//      3-6 | 0-2), split-plane b32 LDS + swz (verified 2-lanes/bank floor).
//      Y fp16 [row][j].
//   K2 collowK2: column bits 0-6 (qubits 10..4), 128x32 tiles, 2 phases,
//      split-plane LDS [d*32+c] (bank floor). Z fp16. (round-5 verbatim)
//   K3 colhighK3: column bits 7-10 (qubits 3..0), registers only,
//      rows at stride 128, writes Re(O) fp32. (round-5 verbatim)
// Round-7 post-mortem: grp-loop + register prefetch spilled (VGPR 64,
// WRITE_SIZE 48MB = +32MB scratch) -> removed. Bank "conflicts" seen were
// the benign 2-way floor (1 cycle/ds op). ~96 MB traffic.

#define DIM 2048
#define NQ 11

__device__ __forceinline__ int swz(int j) { return j ^ ((j >> 5) & 31); }

__device__ __forceinline__ float2 cmul(float2 a, float2 b) {
    return make_float2(a.x * b.x - a.y * b.y, a.x * b.y + a.y * b.x);
}

// Composite gate g = Rz @ Ry @ Rx for qubit q; conj!=0 -> conjugate entries.
__device__ __forceinline__ void make_gate(const float* __restrict__ w, int q,
                                          int conj, float2* out4) {
    const float WM = 0.632455532033675866f;  // sqrt(2/5)
    float hx = 0.5f * WM * w[q * 3 + 0];
    float hy = 0.5f * WM * w[q * 3 + 1];
    float hz = 0.5f * WM * w[q * 3 + 2];
    float cx, sx, cy, sy, cz, sz;
    sincosf(hx, &sx, &cx);
    sincosf(hy, &sy, &cy);
    sincosf(hz, &sz, &cz);
    float2 m00 = make_float2(cy * cx,  sy * sx);
    float2 m01 = make_float2(-sy * cx, -cy * sx);
    float2 m10 = make_float2(sy * cx,  -cy * sx);
    float2 m11 = make_float2(cy * cx,  -sy * sx);
    float2 ez  = make_float2(cz, -sz);
    float2 ezc = make_float2(cz,  sz);
    float2 g00 = cmul(ez, m00);
    float2 g01 = cmul(ez, m01);
    float2 g10 = cmul(ezc, m10);
    float2 g11 = cmul(ezc, m11);
    float sgn = conj ? -1.f : 1.f;
    out4[0] = make_float2(g00.x, sgn * g00.y);
    out4[1] = make_float2(g01.x, sgn * g01.y);
    out4[2] = make_float2(g10.x, sgn * g10.y);
    out4[3] = make_float2(g11.x, sgn * g11.y);
}

__device__ __forceinline__ void bfly(float2& A, float2& B, const float2* g) {
    float2 a = A, b = B;
    A = make_float2(g[0].x * a.x - g[0].y * a.y + g[1].x * b.x - g[1].y * b.y,
                    g[0].x * a.y + g[0].y * a.x + g[1].x * b.y + g[1].y * b.x);
    B = make_float2(g[2].x * a.x - g[2].y * a.y + g[3].x * b.x - g[3].y * b.y,
                    g[2].x * a.y + g[2].y * a.x + g[3].x * b.y + g[3].y * b.x);
}

template <int ST>
__device__ __forceinline__ void stage16(float2* v, const float2* g) {
#pragma unroll
    for (int m = 0; m < 16; ++m)
        if (!(m & ST)) bfly(v[m], v[m + ST], g);
}

__device__ __forceinline__ void load_gate(const float2 (*gsh)[4], int q,
                                          float2* g) {
    g[0] = gsh[q][0]; g[1] = gsh[q][1]; g[2] = gsh[q][2]; g[3] = gsh[q][3];
}

__device__ __forceinline__ unsigned pack_h2(float2 v) {
    __half2 h = __float22half2_rn(v);
    return *reinterpret_cast<unsigned*>(&h);
}
__device__ __forceinline__ float2 unpack_h2(unsigned u) {
    __half2 h = *reinterpret_cast<__half2*>(&u);
    return __half22float2(h);
}

// ---------------- K1: Y = X U^H (row transform, 2 rows/block) --------------
__global__ __launch_bounds__(256, 2) void rowpassK1(
    const float* __restrict__ X, unsigned* __restrict__ Y,
    const float* __restrict__ wt) {
    __shared__ float pRe[2 * DIM];
    __shared__ float pIm[2 * DIM];
    __shared__ float2 gsh[NQ][4];
    int t = threadIdx.x;
    if (t < NQ) make_gate(wt, t, 1, &gsh[t][0]);  // conjugated gates
    __syncthreads();

    int u = t & 127, rv = t >> 7;       // u = j bits 0-6, rv = row-in-block
    int base = rv * DIM;
    int row = blockIdx.x * 2 + rv;
    const float* xrow = X + (size_t)row * DIM;

    // Phase A: j = u + 128m (bits 7-10 -> qubits 3,2,1,0). X real.
    float xr[16];
#pragma unroll
    for (int m = 0; m < 16; ++m) xr[m] = xrow[u + (m << 7)];

    float2 v[16], g[4];
    load_gate(gsh, 3, g);               // j bit 7, real-input stage
#pragma unroll
    for (int m = 0; m < 16; m += 2) {
        float a = xr[m], b = xr[m + 1];
        v[m]     = make_float2(g[0].x * a + g[1].x * b, g[0].y * a + g[1].y * b);
        v[m + 1] = make_float2(g[2].x * a + g[3].x * b, g[2].y * a + g[3].y * b);
    }
    load_gate(gsh, 2, g); stage16<2>(v, g);   // bit 8
    load_gate(gsh, 1, g); stage16<4>(v, g);   // bit 9
    load_gate(gsh, 0, g); stage16<8>(v, g);   // bit 10

#pragma unroll
    for (int m = 0; m < 16; ++m) {
        int a = base + swz(u + (m << 7));
        pRe[a] = v[m].x; pIm[a] = v[m].y;
    }
    __syncthreads();

    // Phase M: j = (u&7) + 8m + 128*(u>>3) (bits 3-6 -> qubits 7,6,5,4).
    int uLo = u & 7, uHi = u >> 3;
#pragma unroll
    for (int m = 0; m < 16; ++m) {
        int a = base + swz(uLo + (m << 3) + (uHi << 7));
        v[m] = make_float2(pRe[a], pIm[a]);
    }
    load_gate(gsh, 7, g); stage16<1>(v, g);
    load_gate(gsh, 6, g); stage16<2>(v, g);
    load_gate(gsh, 5, g); stage16<4>(v, g);
    load_gate(gsh, 4, g); stage16<8>(v, g);
#pragma unroll
    for (int m = 0; m < 16; ++m) {
        int a = base + swz(uLo + (m << 3) + (uHi << 7));
        pRe[a] = v[m].x; pIm[a] = v[m].y;
    }
    __syncthreads();

    // Phase F: j = m + 16u (bits 0-2 -> qubits 10,9,8).
#pragma unroll
    for (int m = 0; m < 16; ++m) {
        int a = base + swz(m + (u << 4));
        v[m] = make_float2(pRe[a], pIm[a]);
    }
    load_gate(gsh, 10, g); stage16<1>(v, g);
    load_gate(gsh, 9, g);  stage16<2>(v, g);
    load_gate(gsh, 8, g);  stage16<4>(v, g);

    // Store fp16: thread holds 16 consecutive j = 16u..16u+15.
    unsigned* yp = Y + (size_t)row * DIM + (u << 4);
#pragma unroll
    for (int e = 0; e < 4; ++e) {
        uint4 pk;
        pk.x = pack_h2(v[4 * e + 0]);
        pk.y = pack_h2(v[4 * e + 1]);
        pk.z = pack_h2(v[4 * e + 2]);
        pk.w = pack_h2(v[4 * e + 3]);
        *reinterpret_cast<uint4*>(yp + 4 * e) = pk;
    }
}

// -------- K2: column transform over row bits 0-6 (qubits 10..4) ------------
// Tile: 128 rows x 32 cols. 256 threads, 16 elems each, 2 phases.
__global__ __launch_bounds__(256, 4) void collowK2(
    const unsigned* __restrict__ Y, unsigned* __restrict__ Z,
    const float* __restrict__ wt) {
    __shared__ float pRe[128 * 32];
    __shared__ float pIm[128 * 32];
    __shared__ float2 gsh[NQ][4];
    int t = threadIdx.x;
    if (t < NQ) make_gate(wt, t, 0, &gsh[t][0]);
    __syncthreads();

    int c = t & 31, rr = t >> 5;         // rr = d bits 0-2 (phase A)
    int r0 = (blockIdx.x >> 6) * 128;    // 16 row groups
    int c0 = (blockIdx.x & 63) * 32;     // 64 col groups

    // Phase A: d = rr + 8m (bits 3-6 -> qubits 7,6,5,4).
    float2 v[16], g[4];
#pragma unroll
    for (int m = 0; m < 16; ++m)
        v[m] = unpack_h2(Y[(size_t)(r0 + rr + (m << 3)) * DIM + c0 + c]);

    load_gate(gsh, 7, g); stage16<1>(v, g);
    load_gate(gsh, 6, g); stage16<2>(v, g);
    load_gate(gsh, 5, g); stage16<4>(v, g);
    load_gate(gsh, 4, g); stage16<8>(v, g);
#pragma unroll
    for (int m = 0; m < 16; ++m) {
        int a = (rr + (m << 3)) * 32 + c;
        pRe[a] = v[m].x; pIm[a] = v[m].y;
    }
    __syncthreads();

    // Phase F: d = m + 16rr (bits 0-2 -> qubits 10,9,8).
#pragma unroll
    for (int m = 0; m < 16; ++m) {
        int a = (m + (rr << 4)) * 32 + c;
        v[m] = make_float2(pRe[a], pIm[a]);
    }
    load_gate(gsh, 10, g); stage16<1>(v, g);
    load_gate(gsh, 9, g);  stage16<2>(v, g);
    load_gate(gsh, 8, g);  stage16<4>(v, g);

#pragma unroll
    for (int m = 0; m < 16; ++m)
        Z[(size_t)(r0 + m + (rr << 4)) * DIM + c0 + c] = pack_h2(v[m]);
}

// -------- K3: column transform over row bits 7-10 (qubits 3..0) ------------
// No LDS: thread owns rows d + 128m for one column j. Writes Re(O) fp32.
__global__ __launch_bounds__(256, 4) void colhighK3(
    const unsigned* __restrict__ Z, float* __restrict__ Out,
    const float* __restrict__ wt, int writeComplex) {
    __shared__ float2 gsh[NQ][4];
    int t = threadIdx.x;
    if (t < NQ) make_gate(wt, t, 0, &gsh[t][0]);
    __syncthreads();

    int b = blockIdx.x;
    int j = (b & 31) * 64 + (t & 63);
    int d = (b >> 5) * 4 + (t >> 6);     // row bits 0-6

    float2 v[16], g[4];
#pragma unroll
    for (int m = 0; m < 16; ++m)
        v[m] = unpack_h2(Z[(size_t)(d + (m << 7)) * DIM + j]);

    load_gate(gsh, 3, g); stage16<1>(v, g);   // row bit 7
    load_gate(gsh, 2, g); stage16<2>(v, g);   // bit 8
    load_gate(gsh, 1, g); stage16<4>(v, g);   // bit 9
    load_gate(gsh, 0, g); stage16<8>(v, g);   // bit 10

    if (!writeComplex) {
#pragma unroll
        for (int m = 0; m < 16; ++m)
            Out[(size_t)(d + (m << 7)) * DIM + j] = v[m].x;
    } else {
        float2* o2 = (float2*)Out;
#pragma unroll
        for (int m = 0; m < 16; ++m)
            o2[(size_t)(d + (m << 7)) * DIM + j] = v[m];
    }
}

extern "C" void kernel_launch(void* const* d_in, const int* in_sizes, int n_in,
                              void* d_out, int out_size, void* d_ws,
                              size_t ws_size, hipStream_t stream) {
    const float* X = (const float*)d_in[0];
    const float* wt = (const float*)d_in[1];
    float* out = (float*)d_out;
    unsigned* Y = (unsigned*)d_ws;                                   // 16 MB
    unsigned* Z = (unsigned*)((char*)d_ws + (size_t)DIM * DIM * 4);  // 16 MB

    rowpassK1<<<DIM / 2, 256, 0, stream>>>(X, Y, wt);
    collowK2<<<16 * 64, 256, 0, stream>>>(Y, Z, wt);
    int wc = (out_size >= 2 * DIM * DIM) ? 1 : 0;
    colhighK3<<<32 * 32, 256, 0, stream>>>(Z, out, wt, wc);
}

// Round 9
// 40.574 us; speedup vs baseline: 1.9007x; 1.0719x over previous
//
#include <hip/hip_runtime.h>
#include <hip/hip_fp16.h>

// O = U X U^H, U = kron of 11 single-qubit SU(2) gates (2048^2 complex64).
// Reordered as O = U * (X * U^H). Structure identical to round-8 (43.5us):
//   K1 rowpassK1: Y = X U^H, 2 rows/block, 3 reg phases, split-plane LDS.
//   K2 collowK2: col bits 0-6, 128x32 tiles, 2 phases. Z fp16.
//   K3 colhighK3: col bits 7-10, registers only, writes Re(O) fp32.
// This round's single lever: butterflies use VOP3P packed fp32
// (v_pk_mul_f32 / v_pk_fma_f32 inline asm, op_sel Re/Im swap, signs baked
// into gate constants) -> 8 instrs/bfly instead of 16. MI355X fp32 peak
// (157 TF) requires v_pk_fma_f32; scalar v_fma is half rate.

#define DIM 2048
#define NQ 11

typedef float v2f __attribute__((ext_vector_type(2)));

__device__ __forceinline__ int swz(int j) { return j ^ ((j >> 5) & 31); }

__device__ __forceinline__ float2 cmul(float2 a, float2 b) {
    return make_float2(a.x * b.x - a.y * b.y, a.x * b.y + a.y * b.x);
}

// ---- VOP3P packed helpers -------------------------------------------------
// d = (s.hi * g.lo, s.lo * g.hi)   [src0 halves swapped]
__device__ __forceinline__ v2f pkmul_swap(v2f s, v2f g) {
    v2f d;
    asm("v_pk_mul_f32 %0, %1, %2 op_sel:[1,0] op_sel_hi:[0,1]"
        : "=v"(d) : "v"(s), "v"(g));
    return d;
}
// d = s0*s1 + c (componentwise)
__device__ __forceinline__ v2f pkfma(v2f s0, v2f s1, v2f c) {
    v2f d;
    asm("v_pk_fma_f32 %0, %1, %2, %3" : "=v"(d) : "v"(s0), "v"(s1), "v"(c));
    return d;
}
// d = (s0.hi*s1.lo + c.lo, s0.lo*s1.hi + c.hi)  [src0 halves swapped]
__device__ __forceinline__ v2f pkfma_swap(v2f s0, v2f s1, v2f c) {
    v2f d;
    asm("v_pk_fma_f32 %0, %1, %2, %3 op_sel:[1,0,0] op_sel_hi:[0,1,1]"
        : "=v"(d) : "v"(s0), "v"(s1), "v"(c));
    return d;
}

// Gate in packed form: per complex entry E -> x=(E.x,E.x), y=(-E.y,+E.y).
struct PkGate {
    v2f x00, y00, x01, y01, x10, y10, x11, y11;
};

// Composite gate g = Rz @ Ry @ Rx for qubit q; conj!=0 -> conjugate entries.
__device__ __forceinline__ void make_gate(const float* __restrict__ w, int q,
                                          int conj, float2* out4) {
    const float WM = 0.632455532033675866f;  // sqrt(2/5)
    float hx = 0.5f * WM * w[q * 3 + 0];
    float hy = 0.5f * WM * w[q * 3 + 1];
    float hz = 0.5f * WM * w[q * 3 + 2];
    float cx, sx, cy, sy, cz, sz;
    sincosf(hx, &sx, &cx);
    sincosf(hy, &sy, &cy);
    sincosf(hz, &sz, &cz);
    float2 m00 = make_float2(cy * cx,  sy * sx);
    float2 m01 = make_float2(-sy * cx, -cy * sx);
    float2 m10 = make_float2(sy * cx,  -cy * sx);
    float2 m11 = make_float2(cy * cx,  -sy * sx);
    float2 ez  = make_float2(cz, -sz);
    float2 ezc = make_float2(cz,  sz);
    float2 g00 = cmul(ez, m00);
    float2 g01 = cmul(ez, m01);
    float2 g10 = cmul(ezc, m10);
    float2 g11 = cmul(ezc, m11);
    float sgn = conj ? -1.f : 1.f;
    out4[0] = make_float2(g00.x, sgn * g00.y);
    out4[1] = make_float2(g01.x, sgn * g01.y);
    out4[2] = make_float2(g10.x, sgn * g10.y);
    out4[3] = make_float2(g11.x, sgn * g11.y);
}

// Build packed-gate LDS table (thread t < NQ builds gate t).
__device__ __forceinline__ void build_pk_gates(const float* __restrict__ wt,
                                               int t, int conj,
                                               v2f (*gsh)[8]) {
    if (t < NQ) {
        float2 e[4];
        make_gate(wt, t, conj, e);
#pragma unroll
        for (int k = 0; k < 4; ++k) {
            v2f px = {e[k].x, e[k].x};
            v2f py = {-e[k].y, e[k].y};
            gsh[t][2 * k + 0] = px;
            gsh[t][2 * k + 1] = py;
        }
    }
}

__device__ __forceinline__ void load_pkgate(const v2f (*gsh)[8], int q,
                                            PkGate& G) {
    G.x00 = gsh[q][0]; G.y00 = gsh[q][1];
    G.x01 = gsh[q][2]; G.y01 = gsh[q][3];
    G.x10 = gsh[q][4]; G.y10 = gsh[q][5];
    G.x11 = gsh[q][6]; G.y11 = gsh[q][7];
}

// Butterfly: (A,B) <- (E00 A + E01 B, E10 A + E11 B), 8 VOP3P instrs.
__device__ __forceinline__ void bfly(float2& A, float2& B, const PkGate& G) {
    v2f a = __builtin_bit_cast(v2f, A), b = __builtin_bit_cast(v2f, B);
    v2f t;
    t = pkmul_swap(b, G.y01);        // (-y01*b.im, y01*b.re)
    t = pkfma(b, G.x01, t);          // + x01*b           = E01*b
    t = pkfma_swap(a, G.y00, t);     // + (-y00*a.im, y00*a.re)
    A = __builtin_bit_cast(float2, pkfma(a, G.x00, t));   // + x00*a
    t = pkmul_swap(b, G.y11);
    t = pkfma(b, G.x11, t);
    t = pkfma_swap(a, G.y10, t);
    B = __builtin_bit_cast(float2, pkfma(a, G.x10, t));
}

template <int ST>
__device__ __forceinline__ void stage16(float2* v, const PkGate& G) {
#pragma unroll
    for (int m = 0; m < 16; ++m)
        if (!(m & ST)) bfly(v[m], v[m + ST], G);
}

__device__ __forceinline__ unsigned pack_h2(float2 v) {
    __half2 h = __float22half2_rn(v);
    return *reinterpret_cast<unsigned*>(&h);
}
__device__ __forceinline__ float2 unpack_h2(unsigned u) {
    __half2 h = *reinterpret_cast<__half2*>(&u);
    return __half22float2(h);
}

// ---------------- K1: Y = X U^H (row transform, 2 rows/block) --------------
__global__ __launch_bounds__(256, 2) void rowpassK1(
    const float* __restrict__ X, unsigned* __restrict__ Y,
    const float* __restrict__ wt) {
    __shared__ float pRe[2 * DIM];
    __shared__ float pIm[2 * DIM];
    __shared__ v2f gsh[NQ][8];
    int t = threadIdx.x;
    build_pk_gates(wt, t, 1, gsh);      // conjugated gates
    __syncthreads();

    int u = t & 127, rv = t >> 7;       // u = j bits 0-6, rv = row-in-block
    int base = rv * DIM;
    int row = blockIdx.x * 2 + rv;
    const float* xrow = X + (size_t)row * DIM;

    // Phase A: j = u + 128m (bits 7-10 -> qubits 3,2,1,0). X real.
    float xr[16];
#pragma unroll
    for (int m = 0; m < 16; ++m) xr[m] = xrow[u + (m << 7)];

    // real-input first stage (j bit 7, qubit 3), scalar form
    float e00x = gsh[3][0][0], e00y = gsh[3][1][1];
    float e01x = gsh[3][2][0], e01y = gsh[3][3][1];
    float e10x = gsh[3][4][0], e10y = gsh[3][5][1];
    float e11x = gsh[3][6][0], e11y = gsh[3][7][1];
    float2 v[16];
#pragma unroll
    for (int m = 0; m < 16; m += 2) {
        float a = xr[m], b = xr[m + 1];
        v[m]     = make_float2(e00x * a + e01x * b, e00y * a + e01y * b);
        v[m + 1] = make_float2(e10x * a + e11x * b, e10y * a + e11y * b);
    }
    PkGate G;
    load_pkgate(gsh, 2, G); stage16<2>(v, G);   // bit 8
    load_pkgate(gsh, 1, G); stage16<4>(v, G);   // bit 9
    load_pkgate(gsh, 0, G); stage16<8>(v, G);   // bit 10

#pragma unroll
    for (int m = 0; m < 16; ++m) {
        int a = base + swz(u + (m << 7));
        pRe[a] = v[m].x; pIm[a] = v[m].y;
    }
    __syncthreads();

    // Phase M: j = (u&7) + 8m + 128*(u>>3) (bits 3-6 -> qubits 7,6,5,4).
    int uLo = u & 7, uHi = u >> 3;
#pragma unroll
    for (int m = 0; m < 16; ++m) {
        int a = base + swz(uLo + (m << 3) + (uHi << 7));
        v[m] = make_float2(pRe[a], pIm[a]);
    }
    load_pkgate(gsh, 7, G); stage16<1>(v, G);
    load_pkgate(gsh, 6, G); stage16<2>(v, G);
    load_pkgate(gsh, 5, G); stage16<4>(v, G);
    load_pkgate(gsh, 4, G); stage16<8>(v, G);
#pragma unroll
    for (int m = 0; m < 16; ++m) {
        int a = base + swz(uLo + (m << 3) + (uHi << 7));
        pRe[a] = v[m].x; pIm[a] = v[m].y;
    }
    __syncthreads();

    // Phase F: j = m + 16u (bits 0-2 -> qubits 10,9,8).
#pragma unroll
    for (int m = 0; m < 16; ++m) {
        int a = base + swz(m + (u << 4));
        v[m] = make_float2(pRe[a], pIm[a]);
    }
    load_pkgate(gsh, 10, G); stage16<1>(v, G);
    load_pkgate(gsh, 9, G);  stage16<2>(v, G);
    load_pkgate(gsh, 8, G);  stage16<4>(v, G);

    // Store fp16: thread holds 16 consecutive j = 16u..16u+15.
    unsigned* yp = Y + (size_t)row * DIM + (u << 4);
#pragma unroll
    for (int e = 0; e < 4; ++e) {
        uint4 pk;
        pk.x = pack_h2(v[4 * e + 0]);
        pk.y = pack_h2(v[4 * e + 1]);
        pk.z = pack_h2(v[4 * e + 2]);
        pk.w = pack_h2(v[4 * e + 3]);
        *reinterpret_cast<uint4*>(yp + 4 * e) = pk;
    }
}

// -------- K2: column transform over row bits 0-6 (qubits 10..4) ------------
// Tile: 128 rows x 32 cols. 256 threads, 16 elems each, 2 phases.
__global__ __launch_bounds__(256, 4) void collowK2(
    const unsigned* __restrict__ Y, unsigned* __restrict__ Z,
    const float* __restrict__ wt) {
    __shared__ float pRe[128 * 32];
    __shared__ float pIm[128 * 32];
    __shared__ v2f gsh[NQ][8];
    int t = threadIdx.x;
    build_pk_gates(wt, t, 0, gsh);
    __syncthreads();

    int c = t & 31, rr = t >> 5;         // rr = d bits 0-2 (phase A)
    int r0 = (blockIdx.x >> 6) * 128;    // 16 row groups
    int c0 = (blockIdx.x & 63) * 32;     // 64 col groups

    // Phase A: d = rr + 8m (bits 3-6 -> qubits 7,6,5,4).
    float2 v[16];
    PkGate G;
#pragma unroll
    for (int m = 0; m < 16; ++m)
        v[m] = unpack_h2(Y[(size_t)(r0 + rr + (m << 3)) * DIM + c0 + c]);

    load_pkgate(gsh, 7, G); stage16<1>(v, G);
    load_pkgate(gsh, 6, G); stage16<2>(v, G);
    load_pkgate(gsh, 5, G); stage16<4>(v, G);
    load_pkgate(gsh, 4, G); stage16<8>(v, G);
#pragma unroll
    for (int m = 0; m < 16; ++m) {
        int a = (rr + (m << 3)) * 32 + c;
        pRe[a] = v[m].x; pIm[a] = v[m].y;
    }
    __syncthreads();

    // Phase F: d = m + 16rr (bits 0-2 -> qubits 10,9,8).
#pragma unroll
    for (int m = 0; m < 16; ++m) {
        int a = (m + (rr << 4)) * 32 + c;
        v[m] = make_float2(pRe[a], pIm[a]);
    }
    load_pkgate(gsh, 10, G); stage16<1>(v, G);
    load_pkgate(gsh, 9, G);  stage16<2>(v, G);
    load_pkgate(gsh, 8, G);  stage16<4>(v, G);

#pragma unroll
    for (int m = 0; m < 16; ++m)
        Z[(size_t)(r0 + m + (rr << 4)) * DIM + c0 + c] = pack_h2(v[m]);
}

// -------- K3: column transform over row bits 7-10 (qubits 3..0) ------------
// No LDS: thread owns rows d + 128m for one column j. Writes Re(O) fp32.
__global__ __launch_bounds__(256, 4) void colhighK3(
    const unsigned* __restrict__ Z, float* __restrict__ Out,
    const float* __restrict__ wt, int writeComplex) {
    __shared__ v2f gsh[NQ][8];
    int t = threadIdx.x;
    build_pk_gates(wt, t, 0, gsh);
    __syncthreads();

    int b = blockIdx.x;
    int j = (b & 31) * 64 + (t & 63);
    int d = (b >> 5) * 4 + (t >> 6);     // row bits 0-6

    float2 v[16];
    PkGate G;
#pragma unroll
    for (int m = 0; m < 16; ++m)
        v[m] = unpack_h2(Z[(size_t)(d + (m << 7)) * DIM + j]);

    load_pkgate(gsh, 3, G); stage16<1>(v, G);   // row bit 7
    load_pkgate(gsh, 2, G); stage16<2>(v, G);   // bit 8
    load_pkgate(gsh, 1, G); stage16<4>(v, G);   // bit 9
    load_pkgate(gsh, 0, G); stage16<8>(v, G);   // bit 10

    if (!writeComplex) {
#pragma unroll
        for (int m = 0; m < 16; ++m)
            Out[(size_t)(d + (m << 7)) * DIM + j] = v[m].x;
    } else {
        float2* o2 = (float2*)Out;
#pragma unroll
        for (int m = 0; m < 16; ++m)
            o2[(size_t)(d + (m << 7)) * DIM + j] = v[m];
    }
}

extern "C" void kernel_launch(void* const* d_in, const int* in_sizes, int n_in,
                              void* d_out, int out_size, void* d_ws,
                              size_t ws_size, hipStream_t stream) {
    const float* X = (const float*)d_in[0];
    const float* wt = (const float*)d_in[1];
    float* out = (float*)d_out;
    unsigned* Y = (unsigned*)d_ws;                                   // 16 MB
    unsigned* Z = (unsigned*)((char*)d_ws + (size_t)DIM * DIM * 4);  // 16 MB

    rowpassK1<<<DIM / 2, 256, 0, stream>>>(X, Y, wt);
    collowK2<<<16 * 64, 256, 0, stream>>>(Y, Z, wt);
    int wc = (out_size >= 2 * DIM * DIM) ? 1 : 0;
    colhighK3<<<32 * 32, 256, 0, stream>>>(Z, out, wt, wc);
}

// Round 10
// 38.578 us; speedup vs baseline: 1.9990x; 1.0517x over previous
//
#include <hip/hip_runtime.h>
#include <hip/hip_fp16.h>

// O = U X U^H, U = kron of 11 single-qubit SU(2) gates (2048^2 complex64).
// Reordered as O = U * (X * U^H). Two kernels:
//   K1 rowpassK1: Y = X U^H (row transform, conj gates). 2 rows/block,
//      3 reg phases, split-plane LDS + swz (round-8 verified). Y fp16
//      COLUMN-BLOCKED: Y[jblk=j>>3][row][jin=j&7] so K2's reads coalesce.
//   K2 colfused: full 11-stage column transform, 8-col strip per block,
//      1024 thr, 16 elems/thread, 3 phases (row bits 7-10 | 3-6 | 0-2),
//      two fp32 split-plane LDS exchanges ([r*9+c] pad, <=4-way banks),
//      writes Re(O) fp32. Eliminates the Z intermediate (32 MB traffic)
//      and one launch vs round-9.
// Butterflies: VOP3P packed fp32 (v_pk_fma_f32, op_sel Re/Im swap, signs
// baked into gate constants) - 8 instrs/bfly. Traffic ~64 MB.

#define DIM 2048
#define NQ 11

typedef float v2f __attribute__((ext_vector_type(2)));

__device__ __forceinline__ int swz(int j) { return j ^ ((j >> 5) & 31); }

__device__ __forceinline__ float2 cmul(float2 a, float2 b) {
    return make_float2(a.x * b.x - a.y * b.y, a.x * b.y + a.y * b.x);
}

// ---- VOP3P packed helpers -------------------------------------------------
__device__ __forceinline__ v2f pkmul_swap(v2f s, v2f g) {
    v2f d;
    asm("v_pk_mul_f32 %0, %1, %2 op_sel:[1,0] op_sel_hi:[0,1]"
        : "=v"(d) : "v"(s), "v"(g));
    return d;
}
__device__ __forceinline__ v2f pkfma(v2f s0, v2f s1, v2f c) {
    v2f d;
    asm("v_pk_fma_f32 %0, %1, %2, %3" : "=v"(d) : "v"(s0), "v"(s1), "v"(c));
    return d;
}
__device__ __forceinline__ v2f pkfma_swap(v2f s0, v2f s1, v2f c) {
    v2f d;
    asm("v_pk_fma_f32 %0, %1, %2, %3 op_sel:[1,0,0] op_sel_hi:[0,1,1]"
        : "=v"(d) : "v"(s0), "v"(s1), "v"(c));
    return d;
}

struct PkGate {
    v2f x00, y00, x01, y01, x10, y10, x11, y11;
};

// Composite gate g = Rz @ Ry @ Rx for qubit q; conj!=0 -> conjugate entries.
__device__ __forceinline__ void make_gate(const float* __restrict__ w, int q,
                                          int conj, float2* out4) {
    const float WM = 0.632455532033675866f;  // sqrt(2/5)
    float hx = 0.5f * WM * w[q * 3 + 0];
    float hy = 0.5f * WM * w[q * 3 + 1];
    float hz = 0.5f * WM * w[q * 3 + 2];
    float cx, sx, cy, sy, cz, sz;
    sincosf(hx, &sx, &cx);
    sincosf(hy, &sy, &cy);
    sincosf(hz, &sz, &cz);
    float2 m00 = make_float2(cy * cx,  sy * sx);
    float2 m01 = make_float2(-sy * cx, -cy * sx);
    float2 m10 = make_float2(sy * cx,  -cy * sx);
    float2 m11 = make_float2(cy * cx,  -sy * sx);
    float2 ez  = make_float2(cz, -sz);
    float2 ezc = make_float2(cz,  sz);
    float2 g00 = cmul(ez, m00);
    float2 g01 = cmul(ez, m01);
    float2 g10 = cmul(ezc, m10);
    float2 g11 = cmul(ezc, m11);
    float sgn = conj ? -1.f : 1.f;
    out4[0] = make_float2(g00.x, sgn * g00.y);
    out4[1] = make_float2(g01.x, sgn * g01.y);
    out4[2] = make_float2(g10.x, sgn * g10.y);
    out4[3] = make_float2(g11.x, sgn * g11.y);
}

__device__ __forceinline__ void build_pk_gates(const float* __restrict__ wt,
                                               int t, int conj,
                                               v2f (*gsh)[8]) {
    if (t < NQ) {
        float2 e[4];
        make_gate(wt, t, conj, e);
#pragma unroll
        for (int k = 0; k < 4; ++k) {
            v2f px = {e[k].x, e[k].x};
            v2f py = {-e[k].y, e[k].y};
            gsh[t][2 * k + 0] = px;
            gsh[t][2 * k + 1] = py;
        }
    }
}

__device__ __forceinline__ void load_pkgate(const v2f (*gsh)[8], int q,
                                            PkGate& G) {
    G.x00 = gsh[q][0]; G.y00 = gsh[q][1];
    G.x01 = gsh[q][2]; G.y01 = gsh[q][3];
    G.x10 = gsh[q][4]; G.y10 = gsh[q][5];
    G.x11 = gsh[q][6]; G.y11 = gsh[q][7];
}

// Butterfly: (A,B) <- (E00 A + E01 B, E10 A + E11 B), 8 VOP3P instrs.
__device__ __forceinline__ void bfly(float2& A, float2& B, const PkGate& G) {
    v2f a = __builtin_bit_cast(v2f, A), b = __builtin_bit_cast(v2f, B);
    v2f t;
    t = pkmul_swap(b, G.y01);
    t = pkfma(b, G.x01, t);
    t = pkfma_swap(a, G.y00, t);
    A = __builtin_bit_cast(float2, pkfma(a, G.x00, t));
    t = pkmul_swap(b, G.y11);
    t = pkfma(b, G.x11, t);
    t = pkfma_swap(a, G.y10, t);
    B = __builtin_bit_cast(float2, pkfma(a, G.x10, t));
}

template <int ST>
__device__ __forceinline__ void stage16(float2* v, const PkGate& G) {
#pragma unroll
    for (int m = 0; m < 16; ++m)
        if (!(m & ST)) bfly(v[m], v[m + ST], G);
}

__device__ __forceinline__ unsigned pack_h2(float2 v) {
    __half2 h = __float22half2_rn(v);
    return *reinterpret_cast<unsigned*>(&h);
}
__device__ __forceinline__ float2 unpack_h2(unsigned u) {
    __half2 h = *reinterpret_cast<__half2*>(&u);
    return __half22float2(h);
}

// ---------------- K1: Y = X U^H (row transform, 2 rows/block) --------------
// Y layout: column-blocked fp16, Y[jblk][row][jin], jblk=j>>3, jin=j&7.
__global__ __launch_bounds__(256, 2) void rowpassK1(
    const float* __restrict__ X, unsigned* __restrict__ Y,
    const float* __restrict__ wt) {
    __shared__ float pRe[2 * DIM];
    __shared__ float pIm[2 * DIM];
    __shared__ v2f gsh[NQ][8];
    int t = threadIdx.x;
    build_pk_gates(wt, t, 1, gsh);      // conjugated gates
    __syncthreads();

    int u = t & 127, rv = t >> 7;       // u = j bits 0-6, rv = row-in-block
    int base = rv * DIM;
    int row = blockIdx.x * 2 + rv;
    const float* xrow = X + (size_t)row * DIM;

    // Phase A: j = u + 128m (bits 7-10 -> qubits 3,2,1,0). X real.
    float xr[16];
#pragma unroll
    for (int m = 0; m < 16; ++m) xr[m] = xrow[u + (m << 7)];

    // real-input first stage (j bit 7, qubit 3), scalar form
    float e00x = gsh[3][0][0], e00y = gsh[3][1][1];
    float e01x = gsh[3][2][0], e01y = gsh[3][3][1];
    float e10x = gsh[3][4][0], e10y = gsh[3][5][1];
    float e11x = gsh[3][6][0], e11y = gsh[3][7][1];
    float2 v[16];
#pragma unroll
    for (int m = 0; m < 16; m += 2) {
        float a = xr[m], b = xr[m + 1];
        v[m]     = make_float2(e00x * a + e01x * b, e00y * a + e01y * b);
        v[m + 1] = make_float2(e10x * a + e11x * b, e10y * a + e11y * b);
    }
    PkGate G;
    load_pkgate(gsh, 2, G); stage16<2>(v, G);   // bit 8
    load_pkgate(gsh, 1, G); stage16<4>(v, G);   // bit 9
    load_pkgate(gsh, 0, G); stage16<8>(v, G);   // bit 10

#pragma unroll
    for (int m = 0; m < 16; ++m) {
        int a = base + swz(u + (m << 7));
        pRe[a] = v[m].x; pIm[a] = v[m].y;
    }
    __syncthreads();

    // Phase M: j = (u&7) + 8m + 128*(u>>3) (bits 3-6 -> qubits 7,6,5,4).
    int uLo = u & 7, uHi = u >> 3;
#pragma unroll
    for (int m = 0; m < 16; ++m) {
        int a = base + swz(uLo + (m << 3) + (uHi << 7));
        v[m] = make_float2(pRe[a], pIm[a]);
    }
    load_pkgate(gsh, 7, G); stage16<1>(v, G);
    load_pkgate(gsh, 6, G); stage16<2>(v, G);
    load_pkgate(gsh, 5, G); stage16<4>(v, G);
    load_pkgate(gsh, 4, G); stage16<8>(v, G);
#pragma unroll
    for (int m = 0; m < 16; ++m) {
        int a = base + swz(uLo + (m << 3) + (uHi << 7));
        pRe[a] = v[m].x; pIm[a] = v[m].y;
    }
    __syncthreads();

    // Phase F: j = m + 16u (bits 0-2 -> qubits 10,9,8).
#pragma unroll
    for (int m = 0; m < 16; ++m) {
        int a = base + swz(m + (u << 4));
        v[m] = make_float2(pRe[a], pIm[a]);
    }
    load_pkgate(gsh, 10, G); stage16<1>(v, G);
    load_pkgate(gsh, 9, G);  stage16<2>(v, G);
    load_pkgate(gsh, 8, G);  stage16<4>(v, G);

    // Store fp16 column-blocked: j = 16u+e -> jblk = 2u + (e>>3), jin = e&7.
    // Two 32B chunks; the 64B line's other half (row^1) comes from the
    // other half of this block -> L2 write-combining.
    unsigned* yp = Y + (size_t)(2 * u) * (DIM * 8) + (size_t)row * 8;
    uint4 pk0, pk1;
    pk0.x = pack_h2(v[0]); pk0.y = pack_h2(v[1]);
    pk0.z = pack_h2(v[2]); pk0.w = pack_h2(v[3]);
    pk1.x = pack_h2(v[4]); pk1.y = pack_h2(v[5]);
    pk1.z = pack_h2(v[6]); pk1.w = pack_h2(v[7]);
    *reinterpret_cast<uint4*>(yp) = pk0;
    *reinterpret_cast<uint4*>(yp + 4) = pk1;
    unsigned* yp2 = yp + DIM * 8;       // jblk = 2u+1
    pk0.x = pack_h2(v[8]);  pk0.y = pack_h2(v[9]);
    pk0.z = pack_h2(v[10]); pk0.w = pack_h2(v[11]);
    pk1.x = pack_h2(v[12]); pk1.y = pack_h2(v[13]);
    pk1.z = pack_h2(v[14]); pk1.w = pack_h2(v[15]);
    *reinterpret_cast<uint4*>(yp2) = pk0;
    *reinterpret_cast<uint4*>(yp2 + 4) = pk1;
}

// -------- K2: full column transform (row bits 0-10), 8-col strip -----------
// 1024 threads, 16 elems/thread. Phases: A bits 7-10 | M bits 3-6 | F 0-2.
// LDS: fp32 split planes, word = r*9 + c (pad-9: <=4-way banks all phases).
__global__ __launch_bounds__(1024, 4) void colfused(
    const unsigned* __restrict__ Y, float* __restrict__ Out,
    const float* __restrict__ wt, int writeComplex) {
    __shared__ float pRe[DIM * 9];
    __shared__ float pIm[DIM * 9];
    __shared__ v2f gsh[NQ][8];
    int t = threadIdx.x;
    build_pk_gates(wt, t, 0, gsh);
    __syncthreads();

    int c = t & 7, u = t >> 3;          // u in 0..127
    const unsigned* yb = Y + (size_t)blockIdx.x * (DIM * 8);

    // Phase A: r = u + 128m (bits 7-10 -> qubits 3,2,1,0).
    float2 v[16];
    PkGate G;
#pragma unroll
    for (int m = 0; m < 16; ++m)
        v[m] = unpack_h2(yb[(u + (m << 7)) * 8 + c]);

    load_pkgate(gsh, 3, G); stage16<1>(v, G);   // bit 7
    load_pkgate(gsh, 2, G); stage16<2>(v, G);   // bit 8
    load_pkgate(gsh, 1, G); stage16<4>(v, G);   // bit 9
    load_pkgate(gsh, 0, G); stage16<8>(v, G);   // bit 10

#pragma unroll
    for (int m = 0; m < 16; ++m) {
        int a = (u + (m << 7)) * 9 + c;
        pRe[a] = v[m].x; pIm[a] = v[m].y;
    }
    __syncthreads();

    // Phase M: r = (u&7) + 8m + 128*(u>>3) (bits 3-6 -> qubits 7,6,5,4).
    int uLo = u & 7, uHi = u >> 3;
#pragma unroll
    for (int m = 0; m < 16; ++m) {
        int a = (uLo + (m << 3) + (uHi << 7)) * 9 + c;
        v[m] = make_float2(pRe[a], pIm[a]);
    }
    load_pkgate(gsh, 7, G); stage16<1>(v, G);
    load_pkgate(gsh, 6, G); stage16<2>(v, G);
    load_pkgate(gsh, 5, G); stage16<4>(v, G);
    load_pkgate(gsh, 4, G); stage16<8>(v, G);
#pragma unroll
    for (int m = 0; m < 16; ++m) {
        int a = (uLo + (m << 3) + (uHi << 7)) * 9 + c;
        pRe[a] = v[m].x; pIm[a] = v[m].y;
    }
    __syncthreads();

    // Phase F: r = m + 16u (bits 0-2 -> qubits 10,9,8; bit 3 already done).
#pragma unroll
    for (int m = 0; m < 16; ++m) {
        int a = (m + (u << 4)) * 9 + c;
        v[m] = make_float2(pRe[a], pIm[a]);
    }
    load_pkgate(gsh, 10, G); stage16<1>(v, G);
    load_pkgate(gsh, 9, G);  stage16<2>(v, G);
    load_pkgate(gsh, 8, G);  stage16<4>(v, G);

    // Write: thread holds rows r = 16u..16u+15 of column j = bx*8 + c.
    int j = blockIdx.x * 8 + c;
    if (!writeComplex) {
#pragma unroll
        for (int m = 0; m < 16; ++m)
            Out[(size_t)(m + (u << 4)) * DIM + j] = v[m].x;
    } else {
        float2* o2 = (float2*)Out;
#pragma unroll
        for (int m = 0; m < 16; ++m)
            o2[(size_t)(m + (u << 4)) * DIM + j] = v[m];
    }
}

extern "C" void kernel_launch(void* const* d_in, const int* in_sizes, int n_in,
                              void* d_out, int out_size, void* d_ws,
                              size_t ws_size, hipStream_t stream) {
    const float* X = (const float*)d_in[0];
    const float* wt = (const float*)d_in[1];
    float* out = (float*)d_out;
    unsigned* Y = (unsigned*)d_ws;      // 16 MB fp16, column-blocked

    rowpassK1<<<DIM / 2, 256, 0, stream>>>(X, Y, wt);
    int wc = (out_size >= 2 * DIM * DIM) ? 1 : 0;
    colfused<<<DIM / 8, 1024, 0, stream>>>(Y, out, wt, wc);
}

// Round 11
// 36.446 us; speedup vs baseline: 2.1159x; 1.0585x over previous
//
#include <hip/hip_runtime.h>
#include <hip/hip_fp16.h>

// O = U X U^H, U = kron of 11 single-qubit SU(2) gates (2048^2 complex64).
// Reordered as O = U * (X * U^H). Two kernels:
//   K1 rowpassK1: Y = X U^H (row transform, conj gates). 2 rows/block,
//      3 reg phases, fp32 split-plane LDS + swz. Y fp16 COLUMN-BLOCKED:
//      Y[jblk=j>>3][row][jin=j&7] so K2's reads coalesce. (round-10 verbatim)
//   K2 colfused: full 11-stage column transform, 8-col strip per block,
//      1024 thr, 16 elems/thread, 3 phases (row bits 7-10 | 3-6 | 0-2).
//      THIS ROUND: LDS = packed half2 (72 KB, was 144) -> 2 blocks/CU and
//      half the DS ops; XCD-aware strip swizzle so adjacent strips (which
//      share output 64B lines) land on the same XCD's L2 (write combine).
// Butterflies: VOP3P packed fp32 (v_pk_fma_f32 + op_sel Re/Im swap, signs
// baked into gate constants) - 8 instrs/bfly. Traffic ~64 MB.

#define DIM 2048
#define NQ 11

typedef float v2f __attribute__((ext_vector_type(2)));

__device__ __forceinline__ int swz(int j) { return j ^ ((j >> 5) & 31); }

__device__ __forceinline__ float2 cmul(float2 a, float2 b) {
    return make_float2(a.x * b.x - a.y * b.y, a.x * b.y + a.y * b.x);
}

// ---- VOP3P packed helpers -------------------------------------------------
__device__ __forceinline__ v2f pkmul_swap(v2f s, v2f g) {
    v2f d;
    asm("v_pk_mul_f32 %0, %1, %2 op_sel:[1,0] op_sel_hi:[0,1]"
        : "=v"(d) : "v"(s), "v"(g));
    return d;
}
__device__ __forceinline__ v2f pkfma(v2f s0, v2f s1, v2f c) {
    v2f d;
    asm("v_pk_fma_f32 %0, %1, %2, %3" : "=v"(d) : "v"(s0), "v"(s1), "v"(c));
    return d;
}
__device__ __forceinline__ v2f pkfma_swap(v2f s0, v2f s1, v2f c) {
    v2f d;
    asm("v_pk_fma_f32 %0, %1, %2, %3 op_sel:[1,0,0] op_sel_hi:[0,1,1]"
        : "=v"(d) : "v"(s0), "v"(s1), "v"(c));
    return d;
}

struct PkGate {
    v2f x00, y00, x01, y01, x10, y10, x11, y11;
};

// Composite gate g = Rz @ Ry @ Rx for qubit q; conj!=0 -> conjugate entries.
__device__ __forceinline__ void make_gate(const float* __restrict__ w, int q,
                                          int conj, float2* out4) {
    const float WM = 0.632455532033675866f;  // sqrt(2/5)
    float hx = 0.5f * WM * w[q * 3 + 0];
    float hy = 0.5f * WM * w[q * 3 + 1];
    float hz = 0.5f * WM * w[q * 3 + 2];
    float cx, sx, cy, sy, cz, sz;
    sincosf(hx, &sx, &cx);
    sincosf(hy, &sy, &cy);
    sincosf(hz, &sz, &cz);
    float2 m00 = make_float2(cy * cx,  sy * sx);
    float2 m01 = make_float2(-sy * cx, -cy * sx);
    float2 m10 = make_float2(sy * cx,  -cy * sx);
    float2 m11 = make_float2(cy * cx,  -sy * sx);
    float2 ez  = make_float2(cz, -sz);
    float2 ezc = make_float2(cz,  sz);
    float2 g00 = cmul(ez, m00);
    float2 g01 = cmul(ez, m01);
    float2 g10 = cmul(ezc, m10);
    float2 g11 = cmul(ezc, m11);
    float sgn = conj ? -1.f : 1.f;
    out4[0] = make_float2(g00.x, sgn * g00.y);
    out4[1] = make_float2(g01.x, sgn * g01.y);
    out4[2] = make_float2(g10.x, sgn * g10.y);
    out4[3] = make_float2(g11.x, sgn * g11.y);
}

__device__ __forceinline__ void build_pk_gates(const float* __restrict__ wt,
                                               int t, int conj,
                                               v2f (*gsh)[8]) {
    if (t < NQ) {
        float2 e[4];
        make_gate(wt, t, conj, e);
#pragma unroll
        for (int k = 0; k < 4; ++k) {
            v2f px = {e[k].x, e[k].x};
            v2f py = {-e[k].y, e[k].y};
            gsh[t][2 * k + 0] = px;
            gsh[t][2 * k + 1] = py;
        }
    }
}

__device__ __forceinline__ void load_pkgate(const v2f (*gsh)[8], int q,
                                            PkGate& G) {
    G.x00 = gsh[q][0]; G.y00 = gsh[q][1];
    G.x01 = gsh[q][2]; G.y01 = gsh[q][3];
    G.x10 = gsh[q][4]; G.y10 = gsh[q][5];
    G.x11 = gsh[q][6]; G.y11 = gsh[q][7];
}

// Butterfly: (A,B) <- (E00 A + E01 B, E10 A + E11 B), 8 VOP3P instrs.
__device__ __forceinline__ void bfly(float2& A, float2& B, const PkGate& G) {
    v2f a = __builtin_bit_cast(v2f, A), b = __builtin_bit_cast(v2f, B);
    v2f t;
    t = pkmul_swap(b, G.y01);
    t = pkfma(b, G.x01, t);
    t = pkfma_swap(a, G.y00, t);
    A = __builtin_bit_cast(float2, pkfma(a, G.x00, t));
    t = pkmul_swap(b, G.y11);
    t = pkfma(b, G.x11, t);
    t = pkfma_swap(a, G.y10, t);
    B = __builtin_bit_cast(float2, pkfma(a, G.x10, t));
}

template <int ST>
__device__ __forceinline__ void stage16(float2* v, const PkGate& G) {
#pragma unroll
    for (int m = 0; m < 16; ++m)
        if (!(m & ST)) bfly(v[m], v[m + ST], G);
}

__device__ __forceinline__ unsigned pack_h2(float2 v) {
    __half2 h = __float22half2_rn(v);
    return *reinterpret_cast<unsigned*>(&h);
}
__device__ __forceinline__ float2 unpack_h2(unsigned u) {
    __half2 h = *reinterpret_cast<__half2*>(&u);
    return __half22float2(h);
}

// ---------------- K1: Y = X U^H (row transform, 2 rows/block) --------------
// Y layout: column-blocked fp16, Y[jblk][row][jin], jblk=j>>3, jin=j&7.
__global__ __launch_bounds__(256, 2) void rowpassK1(
    const float* __restrict__ X, unsigned* __restrict__ Y,
    const float* __restrict__ wt) {
    __shared__ float pRe[2 * DIM];
    __shared__ float pIm[2 * DIM];
    __shared__ v2f gsh[NQ][8];
    int t = threadIdx.x;
    build_pk_gates(wt, t, 1, gsh);      // conjugated gates
    __syncthreads();

    int u = t & 127, rv = t >> 7;       // u = j bits 0-6, rv = row-in-block
    int base = rv * DIM;
    int row = blockIdx.x * 2 + rv;
    const float* xrow = X + (size_t)row * DIM;

    // Phase A: j = u + 128m (bits 7-10 -> qubits 3,2,1,0). X real.
    float xr[16];
#pragma unroll
    for (int m = 0; m < 16; ++m) xr[m] = xrow[u + (m << 7)];

    // real-input first stage (j bit 7, qubit 3), scalar form
    float e00x = gsh[3][0][0], e00y = gsh[3][1][1];
    float e01x = gsh[3][2][0], e01y = gsh[3][3][1];
    float e10x = gsh[3][4][0], e10y = gsh[3][5][1];
    float e11x = gsh[3][6][0], e11y = gsh[3][7][1];
    float2 v[16];
#pragma unroll
    for (int m = 0; m < 16; m += 2) {
        float a = xr[m], b = xr[m + 1];
        v[m]     = make_float2(e00x * a + e01x * b, e00y * a + e01y * b);
        v[m + 1] = make_float2(e10x * a + e11x * b, e10y * a + e11y * b);
    }
    PkGate G;
    load_pkgate(gsh, 2, G); stage16<2>(v, G);   // bit 8
    load_pkgate(gsh, 1, G); stage16<4>(v, G);   // bit 9
    load_pkgate(gsh, 0, G); stage16<8>(v, G);   // bit 10

#pragma unroll
    for (int m = 0; m < 16; ++m) {
        int a = base + swz(u + (m << 7));
        pRe[a] = v[m].x; pIm[a] = v[m].y;
    }
    __syncthreads();

    // Phase M: j = (u&7) + 8m + 128*(u>>3) (bits 3-6 -> qubits 7,6,5,4).
    int uLo = u & 7, uHi = u >> 3;
#pragma unroll
    for (int m = 0; m < 16; ++m) {
        int a = base + swz(uLo + (m << 3) + (uHi << 7));
        v[m] = make_float2(pRe[a], pIm[a]);
    }
    load_pkgate(gsh, 7, G); stage16<1>(v, G);
    load_pkgate(gsh, 6, G); stage16<2>(v, G);
    load_pkgate(gsh, 5, G); stage16<4>(v, G);
    load_pkgate(gsh, 4, G); stage16<8>(v, G);
#pragma unroll
    for (int m = 0; m < 16; ++m) {
        int a = base + swz(uLo + (m << 3) + (uHi << 7));
        pRe[a] = v[m].x; pIm[a] = v[m].y;
    }
    __syncthreads();

    // Phase F: j = m + 16u (bits 0-2 -> qubits 10,9,8).
#pragma unroll
    for (int m = 0; m < 16; ++m) {
        int a = base + swz(m + (u << 4));
        v[m] = make_float2(pRe[a], pIm[a]);
    }
    load_pkgate(gsh, 10, G); stage16<1>(v, G);
    load_pkgate(gsh, 9, G);  stage16<2>(v, G);
    load_pkgate(gsh, 8, G);  stage16<4>(v, G);

    // Store fp16 column-blocked: j = 16u+e -> jblk = 2u + (e>>3), jin = e&7.
    unsigned* yp = Y + (size_t)(2 * u) * (DIM * 8) + (size_t)row * 8;
    uint4 pk0, pk1;
    pk0.x = pack_h2(v[0]); pk0.y = pack_h2(v[1]);
    pk0.z = pack_h2(v[2]); pk0.w = pack_h2(v[3]);
    pk1.x = pack_h2(v[4]); pk1.y = pack_h2(v[5]);
    pk1.z = pack_h2(v[6]); pk1.w = pack_h2(v[7]);
    *reinterpret_cast<uint4*>(yp) = pk0;
    *reinterpret_cast<uint4*>(yp + 4) = pk1;
    unsigned* yp2 = yp + DIM * 8;       // jblk = 2u+1
    pk0.x = pack_h2(v[8]);  pk0.y = pack_h2(v[9]);
    pk0.z = pack_h2(v[10]); pk0.w = pack_h2(v[11]);
    pk1.x = pack_h2(v[12]); pk1.y = pack_h2(v[13]);
    pk1.z = pack_h2(v[14]); pk1.w = pack_h2(v[15]);
    *reinterpret_cast<uint4*>(yp2) = pk0;
    *reinterpret_cast<uint4*>(yp2 + 4) = pk1;
}

// -------- K2: full column transform (row bits 0-10), 8-col strip -----------
// 1024 threads, 16 elems/thread. Phases: A bits 7-10 | M bits 3-6 | F 0-2.
// LDS: packed half2 (u32), word = r*9 + c (pad-9, <=4-way banks). 72 KB ->
// 2 resident blocks/CU. Strip chosen XCD-aware: adjacent strips (sharing
// output 64B lines) map to the same XCD.
__global__ __launch_bounds__(1024, 4) void colfused(
    const unsigned* __restrict__ Y, float* __restrict__ Out,
    const float* __restrict__ wt, int writeComplex) {
    __shared__ unsigned pk[DIM * 9];
    __shared__ v2f gsh[NQ][8];
    int t = threadIdx.x;
    build_pk_gates(wt, t, 0, gsh);
    __syncthreads();

    // XCD swizzle (8 XCDs, 256 blocks): strips 32k..32k+31 share XCD k.
    int strip = ((blockIdx.x & 7) << 5) + (blockIdx.x >> 3);

    int c = t & 7, u = t >> 3;          // u in 0..127
    const unsigned* yb = Y + (size_t)strip * (DIM * 8);

    // Phase A: r = u + 128m (bits 7-10 -> qubits 3,2,1,0).
    float2 v[16];
    PkGate G;
#pragma unroll
    for (int m = 0; m < 16; ++m)
        v[m] = unpack_h2(yb[(u + (m << 7)) * 8 + c]);

    load_pkgate(gsh, 3, G); stage16<1>(v, G);   // bit 7
    load_pkgate(gsh, 2, G); stage16<2>(v, G);   // bit 8
    load_pkgate(gsh, 1, G); stage16<4>(v, G);   // bit 9
    load_pkgate(gsh, 0, G); stage16<8>(v, G);   // bit 10

#pragma unroll
    for (int m = 0; m < 16; ++m)
        pk[(u + (m << 7)) * 9 + c] = pack_h2(v[m]);
    __syncthreads();

    // Phase M: r = (u&7) + 8m + 128*(u>>3) (bits 3-6 -> qubits 7,6,5,4).
    int uLo = u & 7, uHi = u >> 3;
#pragma unroll
    for (int m = 0; m < 16; ++m)
        v[m] = unpack_h2(pk[(uLo + (m << 3) + (uHi << 7)) * 9 + c]);
    load_pkgate(gsh, 7, G); stage16<1>(v, G);
    load_pkgate(gsh, 6, G); stage16<2>(v, G);
    load_pkgate(gsh, 5, G); stage16<4>(v, G);
    load_pkgate(gsh, 4, G); stage16<8>(v, G);
#pragma unroll
    for (int m = 0; m < 16; ++m)
        pk[(uLo + (m << 3) + (uHi << 7)) * 9 + c] = pack_h2(v[m]);
    __syncthreads();

    // Phase F: r = m + 16u (bits 0-2 -> qubits 10,9,8).
#pragma unroll
    for (int m = 0; m < 16; ++m)
        v[m] = unpack_h2(pk[(m + (u << 4)) * 9 + c]);
    load_pkgate(gsh, 10, G); stage16<1>(v, G);
    load_pkgate(gsh, 9, G);  stage16<2>(v, G);
    load_pkgate(gsh, 8, G);  stage16<4>(v, G);

    // Write: thread holds rows r = 16u..16u+15 of column j = strip*8 + c.
    int j = strip * 8 + c;
    if (!writeComplex) {
#pragma unroll
        for (int m = 0; m < 16; ++m)
            Out[(size_t)(m + (u << 4)) * DIM + j] = v[m].x;
    } else {
        float2* o2 = (float2*)Out;
#pragma unroll
        for (int m = 0; m < 16; ++m)
            o2[(size_t)(m + (u << 4)) * DIM + j] = v[m];
    }
}

extern "C" void kernel_launch(void* const* d_in, const int* in_sizes, int n_in,
                              void* d_out, int out_size, void* d_ws,
                              size_t ws_size, hipStream_t stream) {
    const float* X = (const float*)d_in[0];
    const float* wt = (const float*)d_in[1];
    float* out = (float*)d_out;
    unsigned* Y = (unsigned*)d_ws;      // 16 MB fp16, column-blocked

    rowpassK1<<<DIM / 2, 256, 0, stream>>>(X, Y, wt);
    int wc = (out_size >= 2 * DIM * DIM) ? 1 : 0;
    colfused<<<DIM / 8, 1024, 0, stream>>>(Y, out, wt, wc);
}

// Round 13
// 35.282 us; speedup vs baseline: 2.1857x; 1.0330x over previous
//
#include <hip/hip_runtime.h>
#include <hip/hip_fp16.h>

// O = U X U^H, U = kron of 11 single-qubit SU(2) gates (2048^2 complex64).
// Reordered as O = U * (X * U^H). Two kernels:
//   K1 rowpassK1: Y = X U^H (row transform, conj gates). THIS ROUND:
//      1 row per 128-thread block (2048 blocks; was 2 rows/256 thr) ->
//      smaller barrier scope, ~8 independent blocks/CU. fp32 split-plane
//      LDS + swz (round-11-verified; the round-12 packed-LDS +
//      launch_bounds(,4) combo caused an unexplained post-timing
//      divergence and is fully reverted). Y fp16 COLUMN-BLOCKED:
//      Y[jblk=j>>3][row][jin=j&7].
//   K2 colfused: full 11-stage column transform, 8-col strip per block,
//      1024 thr, 16 elems/thread, 3 phases. Packed half2 LDS (72 KB),
//      XCD-aware strip swizzle. (round-11 verbatim, passed twice)
// Butterflies: VOP3P packed fp32 (v_pk_fma_f32 + op_sel Re/Im swap, signs
// baked into gate constants) - 8 instrs/bfly. Traffic ~64 MB.

#define DIM 2048
#define NQ 11

typedef float v2f __attribute__((ext_vector_type(2)));

__device__ __forceinline__ int swz(int j) { return j ^ ((j >> 5) & 31); }

__device__ __forceinline__ float2 cmul(float2 a, float2 b) {
    return make_float2(a.x * b.x - a.y * b.y, a.x * b.y + a.y * b.x);
}

// ---- VOP3P packed helpers -------------------------------------------------
__device__ __forceinline__ v2f pkmul_swap(v2f s, v2f g) {
    v2f d;
    asm("v_pk_mul_f32 %0, %1, %2 op_sel:[1,0] op_sel_hi:[0,1]"
        : "=v"(d) : "v"(s), "v"(g));
    return d;
}
__device__ __forceinline__ v2f pkfma(v2f s0, v2f s1, v2f c) {
    v2f d;
    asm("v_pk_fma_f32 %0, %1, %2, %3" : "=v"(d) : "v"(s0), "v"(s1), "v"(c));
    return d;
}
__device__ __forceinline__ v2f pkfma_swap(v2f s0, v2f s1, v2f c) {
    v2f d;
    asm("v_pk_fma_f32 %0, %1, %2, %3 op_sel:[1,0,0] op_sel_hi:[0,1,1]"
        : "=v"(d) : "v"(s0), "v"(s1), "v"(c));
    return d;
}

struct PkGate {
    v2f x00, y00, x01, y01, x10, y10, x11, y11;
};

// Composite gate g = Rz @ Ry @ Rx for qubit q; conj!=0 -> conjugate entries.
__device__ __forceinline__ void make_gate(const float* __restrict__ w, int q,
                                          int conj, float2* out4) {
    const float WM = 0.632455532033675866f;  // sqrt(2/5)
    float hx = 0.5f * WM * w[q * 3 + 0];
    float hy = 0.5f * WM * w[q * 3 + 1];
    float hz = 0.5f * WM * w[q * 3 + 2];
    float cx, sx, cy, sy, cz, sz;
    sincosf(hx, &sx, &cx);
    sincosf(hy, &sy, &cy);
    sincosf(hz, &sz, &cz);
    float2 m00 = make_float2(cy * cx,  sy * sx);
    float2 m01 = make_float2(-sy * cx, -cy * sx);
    float2 m10 = make_float2(sy * cx,  -cy * sx);
    float2 m11 = make_float2(cy * cx,  -sy * sx);
    float2 ez  = make_float2(cz, -sz);
    float2 ezc = make_float2(cz,  sz);
    float2 g00 = cmul(ez, m00);
    float2 g01 = cmul(ez, m01);
    float2 g10 = cmul(ezc, m10);
    float2 g11 = cmul(ezc, m11);
    float sgn = conj ? -1.f : 1.f;
    out4[0] = make_float2(g00.x, sgn * g00.y);
    out4[1] = make_float2(g01.x, sgn * g01.y);
    out4[2] = make_float2(g10.x, sgn * g10.y);
    out4[3] = make_float2(g11.x, sgn * g11.y);
}

__device__ __forceinline__ void build_pk_gates(const float* __restrict__ wt,
                                               int t, int conj,
                                               v2f (*gsh)[8]) {
    if (t < NQ) {
        float2 e[4];
        make_gate(wt, t, conj, e);
#pragma unroll
        for (int k = 0; k < 4; ++k) {
            v2f px = {e[k].x, e[k].x};
            v2f py = {-e[k].y, e[k].y};
            gsh[t][2 * k + 0] = px;
            gsh[t][2 * k + 1] = py;
        }
    }
}

__device__ __forceinline__ void load_pkgate(const v2f (*gsh)[8], int q,
                                            PkGate& G) {
    G.x00 = gsh[q][0]; G.y00 = gsh[q][1];
    G.x01 = gsh[q][2]; G.y01 = gsh[q][3];
    G.x10 = gsh[q][4]; G.y10 = gsh[q][5];
    G.x11 = gsh[q][6]; G.y11 = gsh[q][7];
}

// Butterfly: (A,B) <- (E00 A + E01 B, E10 A + E11 B), 8 VOP3P instrs.
__device__ __forceinline__ void bfly(float2& A, float2& B, const PkGate& G) {
    v2f a = __builtin_bit_cast(v2f, A), b = __builtin_bit_cast(v2f, B);
    v2f t;
    t = pkmul_swap(b, G.y01);
    t = pkfma(b, G.x01, t);
    t = pkfma_swap(a, G.y00, t);
    A = __builtin_bit_cast(float2, pkfma(a, G.x00, t));
    t = pkmul_swap(b, G.y11);
    t = pkfma(b, G.x11, t);
    t = pkfma_swap(a, G.y10, t);
    B = __builtin_bit_cast(float2, pkfma(a, G.x10, t));
}

template <int ST>
__device__ __forceinline__ void stage16(float2* v, const PkGate& G) {
#pragma unroll
    for (int m = 0; m < 16; ++m)
        if (!(m & ST)) bfly(v[m], v[m + ST], G);
}

__device__ __forceinline__ unsigned pack_h2(float2 v) {
    __half2 h = __float22half2_rn(v);
    return *reinterpret_cast<unsigned*>(&h);
}
__device__ __forceinline__ float2 unpack_h2(unsigned u) {
    __half2 h = *reinterpret_cast<__half2*>(&u);
    return __half22float2(h);
}

// ---------------- K1: Y = X U^H (row transform, 1 row/block) ---------------
// 128 threads, 2048 blocks. fp32 split-plane LDS + swz (2-way banks).
// Y layout: column-blocked fp16, Y[jblk][row][jin], jblk=j>>3, jin=j&7.
__global__ __launch_bounds__(128, 2) void rowpassK1(
    const float* __restrict__ X, unsigned* __restrict__ Y,
    const float* __restrict__ wt) {
    __shared__ float pRe[DIM];
    __shared__ float pIm[DIM];
    __shared__ v2f gsh[NQ][8];
    int u = threadIdx.x;                // u = j bits 0-6
    build_pk_gates(wt, u, 1, gsh);      // conjugated gates
    __syncthreads();

    int row = blockIdx.x;
    const float* xrow = X + (size_t)row * DIM;

    // Phase A: j = u + 128m (bits 7-10 -> qubits 3,2,1,0). X real.
    float xr[16];
#pragma unroll
    for (int m = 0; m < 16; ++m) xr[m] = xrow[u + (m << 7)];

    // real-input first stage (j bit 7, qubit 3), scalar form
    float e00x = gsh[3][0][0], e00y = gsh[3][1][1];
    float e01x = gsh[3][2][0], e01y = gsh[3][3][1];
    float e10x = gsh[3][4][0], e10y = gsh[3][5][1];
    float e11x = gsh[3][6][0], e11y = gsh[3][7][1];
    float2 v[16];
#pragma unroll
    for (int m = 0; m < 16; m += 2) {
        float a = xr[m], b = xr[m + 1];
        v[m]     = make_float2(e00x * a + e01x * b, e00y * a + e01y * b);
        v[m + 1] = make_float2(e10x * a + e11x * b, e10y * a + e11y * b);
    }
    PkGate G;
    load_pkgate(gsh, 2, G); stage16<2>(v, G);   // bit 8
    load_pkgate(gsh, 1, G); stage16<4>(v, G);   // bit 9
    load_pkgate(gsh, 0, G); stage16<8>(v, G);   // bit 10

#pragma unroll
    for (int m = 0; m < 16; ++m) {
        int a = swz(u + (m << 7));
        pRe[a] = v[m].x; pIm[a] = v[m].y;
    }
    __syncthreads();

    // Phase M: j = (u&7) + 8m + 128*(u>>3) (bits 3-6 -> qubits 7,6,5,4).
    int uLo = u & 7, uHi = u >> 3;
#pragma unroll
    for (int m = 0; m < 16; ++m) {
        int a = swz(uLo + (m << 3) + (uHi << 7));
        v[m] = make_float2(pRe[a], pIm[a]);
    }
    load_pkgate(gsh, 7, G); stage16<1>(v, G);
    load_pkgate(gsh, 6, G); stage16<2>(v, G);
    load_pkgate(gsh, 5, G); stage16<4>(v, G);
    load_pkgate(gsh, 4, G); stage16<8>(v, G);
#pragma unroll
    for (int m = 0; m < 16; ++m) {
        int a = swz(uLo + (m << 3) + (uHi << 7));
        pRe[a] = v[m].x; pIm[a] = v[m].y;
    }
    __syncthreads();

    // Phase F: j = m + 16u (bits 0-2 -> qubits 10,9,8).
#pragma unroll
    for (int m = 0; m < 16; ++m) {
        int a = swz(m + (u << 4));
        v[m] = make_float2(pRe[a], pIm[a]);
    }
    load_pkgate(gsh, 10, G); stage16<1>(v, G);
    load_pkgate(gsh, 9, G);  stage16<2>(v, G);
    load_pkgate(gsh, 8, G);  stage16<4>(v, G);

    // Store fp16 column-blocked: j = 16u+e -> jblk = 2u + (e>>3), jin = e&7.
    unsigned* yp = Y + (size_t)(2 * u) * (DIM * 8) + (size_t)row * 8;
    uint4 pk0, pk1;
    pk0.x = pack_h2(v[0]); pk0.y = pack_h2(v[1]);
    pk0.z = pack_h2(v[2]); pk0.w = pack_h2(v[3]);
    pk1.x = pack_h2(v[4]); pk1.y = pack_h2(v[5]);
    pk1.z = pack_h2(v[6]); pk1.w = pack_h2(v[7]);
    *reinterpret_cast<uint4*>(yp) = pk0;
    *reinterpret_cast<uint4*>(yp + 4) = pk1;
    unsigned* yp2 = yp + DIM * 8;       // jblk = 2u+1
    pk0.x = pack_h2(v[8]);  pk0.y = pack_h2(v[9]);
    pk0.z = pack_h2(v[10]); pk0.w = pack_h2(v[11]);
    pk1.x = pack_h2(v[12]); pk1.y = pack_h2(v[13]);
    pk1.z = pack_h2(v[14]); pk1.w = pack_h2(v[15]);
    *reinterpret_cast<uint4*>(yp2) = pk0;
    *reinterpret_cast<uint4*>(yp2 + 4) = pk1;
}

// -------- K2: full column transform (row bits 0-10), 8-col strip -----------
// 1024 threads, 16 elems/thread. Phases: A bits 7-10 | M bits 3-6 | F 0-2.
// LDS: packed half2 (u32), word = r*9 + c (pad-9, <=4-way banks). 72 KB ->
// 2 resident blocks/CU. XCD-aware strip swizzle. (round-11 verbatim)
__global__ __launch_bounds__(1024, 4) void colfused(
    const unsigned* __restrict__ Y, float* __restrict__ Out,
    const float* __restrict__ wt, int writeComplex) {
    __shared__ unsigned pk[DIM * 9];
    __shared__ v2f gsh[NQ][8];
    int t = threadIdx.x;
    build_pk_gates(wt, t, 0, gsh);
    __syncthreads();

    // XCD swizzle (8 XCDs, 256 blocks): strips 32k..32k+31 share XCD k.
    int strip = ((blockIdx.x & 7) << 5) + (blockIdx.x >> 3);

    int c = t & 7, u = t >> 3;          // u in 0..127
    const unsigned* yb = Y + (size_t)strip * (DIM * 8);

    // Phase A: r = u + 128m (bits 7-10 -> qubits 3,2,1,0).
    float2 v[16];
    PkGate G;
#pragma unroll
    for (int m = 0; m < 16; ++m)
        v[m] = unpack_h2(yb[(u + (m << 7)) * 8 + c]);

    load_pkgate(gsh, 3, G); stage16<1>(v, G);   // bit 7
    load_pkgate(gsh, 2, G); stage16<2>(v, G);   // bit 8
    load_pkgate(gsh, 1, G); stage16<4>(v, G);   // bit 9
    load_pkgate(gsh, 0, G); stage16<8>(v, G);   // bit 10

#pragma unroll
    for (int m = 0; m < 16; ++m)
        pk[(u + (m << 7)) * 9 + c] = pack_h2(v[m]);
    __syncthreads();

    // Phase M: r = (u&7) + 8m + 128*(u>>3) (bits 3-6 -> qubits 7,6,5,4).
    int uLo = u & 7, uHi = u >> 3;
#pragma unroll
    for (int m = 0; m < 16; ++m)
        v[m] = unpack_h2(pk[(uLo + (m << 3) + (uHi << 7)) * 9 + c]);
    load_pkgate(gsh, 7, G); stage16<1>(v, G);
    load_pkgate(gsh, 6, G); stage16<2>(v, G);
    load_pkgate(gsh, 5, G); stage16<4>(v, G);
    load_pkgate(gsh, 4, G); stage16<8>(v, G);
#pragma unroll
    for (int m = 0; m < 16; ++m)
        pk[(uLo + (m << 3) + (uHi << 7)) * 9 + c] = pack_h2(v[m]);
    __syncthreads();

    // Phase F: r = m + 16u (bits 0-2 -> qubits 10,9,8).
#pragma unroll
    for (int m = 0; m < 16; ++m)
        v[m] = unpack_h2(pk[(m + (u << 4)) * 9 + c]);
    load_pkgate(gsh, 10, G); stage16<1>(v, G);
    load_pkgate(gsh, 9, G);  stage16<2>(v, G);
    load_pkgate(gsh, 8, G);  stage16<4>(v, G);

    // Write: thread holds rows r = 16u..16u+15 of column j = strip*8 + c.
    int j = strip * 8 + c;
    if (!writeComplex) {
#pragma unroll
        for (int m = 0; m < 16; ++m)
            Out[(size_t)(m + (u << 4)) * DIM + j] = v[m].x;
    } else {
        float2* o2 = (float2*)Out;
#pragma unroll
        for (int m = 0; m < 16; ++m)
            o2[(size_t)(m + (u << 4)) * DIM + j] = v[m];
    }
}

extern "C" void kernel_launch(void* const* d_in, const int* in_sizes, int n_in,
                              void* d_out, int out_size, void* d_ws,
                              size_t ws_size, hipStream_t stream) {
    const float* X = (const float*)d_in[0];
    const float* wt = (const float*)d_in[1];
    float* out = (float*)d_out;
    unsigned* Y = (unsigned*)d_ws;      // 16 MB fp16, column-blocked

    rowpassK1<<<DIM, 128, 0, stream>>>(X, Y, wt);
    int wc = (out_size >= 2 * DIM * DIM) ? 1 : 0;
    colfused<<<DIM / 8, 1024, 0, stream>>>(Y, out, wt, wc);
}